// Round 2
// baseline (2311.941 us; speedup 1.0000x reference)
//
#include <hip/hip_runtime.h>
#include <hip/hip_bf16.h>

#define N_PTS 50000
#define KNB   16
#define CH    128
#define CVQ   16           // CV
#define EDGES (N_PTS * KNB)
#define EPS   1e-5f

// ---------------- K1: rel_pos first/second moments -> stats[9] ----------------
__global__ void k_stats(const float* __restrict__ rel, float* __restrict__ stats) {
    float a0=0,a1=0,a2=0,q00=0,q01=0,q02=0,q11=0,q12=0,q22=0;
    int stride = gridDim.x * blockDim.x;
    for (int e = blockIdx.x * blockDim.x + threadIdx.x; e < EDGES; e += stride) {
        float r0 = rel[3*e], r1 = rel[3*e+1], r2 = rel[3*e+2];
        a0 += r0; a1 += r1; a2 += r2;
        q00 = fmaf(r0,r0,q00); q01 = fmaf(r0,r1,q01); q02 = fmaf(r0,r2,q02);
        q11 = fmaf(r1,r1,q11); q12 = fmaf(r1,r2,q12); q22 = fmaf(r2,r2,q22);
    }
    float v[9] = {a0,a1,a2,q00,q01,q02,q11,q12,q22};
    #pragma unroll
    for (int i = 0; i < 9; ++i)
        for (int off = 32; off > 0; off >>= 1)
            v[i] += __shfl_down(v[i], off);
    if ((threadIdx.x & 63) == 0) {
        #pragma unroll
        for (int i = 0; i < 9; ++i) atomicAdd(&stats[i], v[i]);
    }
}

// ---------------- K2: fold BN into W_pos -> fold[c] = {w0',w1',w2',shift} -----
__global__ void k_fold(const float* __restrict__ stats, const float* __restrict__ Wpos,
                       const float* __restrict__ gamma, const float* __restrict__ beta,
                       float4* __restrict__ fold) {
    int c = threadIdx.x;
    if (c >= CH) return;
    const float invE = 1.0f / (float)EDGES;
    float m0 = stats[0]*invE, m1 = stats[1]*invE, m2 = stats[2]*invE;
    float S00 = stats[3]*invE, S01 = stats[4]*invE, S02 = stats[5]*invE;
    float S11 = stats[6]*invE, S12 = stats[7]*invE, S22 = stats[8]*invE;
    float w0 = Wpos[c], w1 = Wpos[CH + c], w2 = Wpos[2*CH + c];
    float mu  = m0*w0 + m1*w1 + m2*w2;
    float Ep2 = w0*w0*S00 + w1*w1*S11 + w2*w2*S22
              + 2.0f*(w0*w1*S01 + w0*w2*S02 + w1*w2*S12);
    float var = Ep2 - mu*mu;
    float sc  = rsqrtf(var + EPS) * gamma[c];
    float sh  = beta[c] - mu * sc;
    fold[c] = make_float4(w0*sc, w1*sc, w2*sc, sh);
}

// ---------------- K3: fused mixer + value + exp + scatter-accumulate ----------
// segb layout: [N][32] floats, [n][0..15]=den (sum of exp), [n][16..31]=num.
__global__ __launch_bounds__(256)
void k_main(const float* __restrict__ xn, const float* __restrict__ rel,
            const int* __restrict__ idx, const float4* __restrict__ fold,
            const float* __restrict__ Wmix, const float* __restrict__ bmix,
            const float* __restrict__ Wval, const float* __restrict__ bval,
            float* __restrict__ segb) {
    __shared__ float4 sTop[CH][4];   // W_mix rows 0..127  (pos_emb part)
    __shared__ float4 sBot[CH][4];   // W_mix rows 128..255 (xn part)
    __shared__ float4 sVal[CH][4];   // W_val
    __shared__ float4 sFold[CH];
    __shared__ float  sBm[CVQ], sBv[CVQ];

    int tid = threadIdx.x;
    for (int i = tid; i < CH*4; i += 256) {
        sTop[i >> 2][i & 3] = ((const float4*)Wmix)[i];
        sBot[i >> 2][i & 3] = ((const float4*)Wmix)[CH*4 + i];
        sVal[i >> 2][i & 3] = ((const float4*)Wval)[i];
    }
    for (int i = tid; i < CH; i += 256) sFold[i] = fold[i];
    if (tid < CVQ) { sBm[tid] = bmix[tid]; sBv[tid] = bval[tid]; }
    __syncthreads();

    int e = blockIdx.x * 256 + tid;
    if (e >= EDGES) return;

    float r0 = rel[3*e], r1 = rel[3*e+1], r2 = rel[3*e+2];
    int   n  = idx[e];

    float z[CVQ], v[CVQ];
    #pragma unroll
    for (int j = 0; j < CVQ; ++j) { z[j] = sBm[j]; v[j] = sBv[j]; }

    const float4* x4 = (const float4*)(xn + (size_t)e * CH);
    #pragma unroll 2
    for (int cc = 0; cc < CH/4; ++cc) {
        float4 xv = x4[cc];
        #pragma unroll
        for (int k = 0; k < 4; ++k) {
            int c = cc*4 + k;
            float x1 = (&xv.x)[k];
            float4 f = sFold[c];
            float pe = fmaf(r2, f.z, fmaf(r1, f.y, fmaf(r0, f.x, f.w)));
            pe = fmaxf(pe, 0.0f);
            #pragma unroll
            for (int q = 0; q < 4; ++q) {
                float4 wt = sTop[c][q], wb = sBot[c][q], wv = sVal[c][q];
                z[q*4+0] = fmaf(pe, wt.x, fmaf(x1, wb.x, z[q*4+0]));
                z[q*4+1] = fmaf(pe, wt.y, fmaf(x1, wb.y, z[q*4+1]));
                z[q*4+2] = fmaf(pe, wt.z, fmaf(x1, wb.z, z[q*4+2]));
                z[q*4+3] = fmaf(pe, wt.w, fmaf(x1, wb.w, z[q*4+3]));
                v[q*4+0] = fmaf(x1, wv.x, v[q*4+0]);
                v[q*4+1] = fmaf(x1, wv.y, v[q*4+1]);
                v[q*4+2] = fmaf(x1, wv.z, v[q*4+2]);
                v[q*4+3] = fmaf(x1, wv.w, v[q*4+3]);
            }
        }
    }

    size_t base = (size_t)n * 32;
    #pragma unroll
    for (int j = 0; j < CVQ; ++j) {
        float ez = __expf(fmaxf(z[j], 0.0f));   // softmax without max-shift (z bounded)
        float vz = fmaxf(v[j], 0.0f) * ez;
        atomicAdd(&segb[base + j], ez);          // den
        atomicAdd(&segb[base + 16 + j], vz);     // num
    }
}

// ---------------- K4: out = x_center + tile(num/den) --------------------------
__global__ __launch_bounds__(256)
void k_out(const float* __restrict__ xc, const float* __restrict__ segb,
           float* __restrict__ out) {
    int i = blockIdx.x * blockDim.x + threadIdx.x;   // float4 index
    const int total = N_PTS * CH / 4;
    if (i >= total) return;
    int n  = i >> 5;          // 32 float4 per row
    int cc = i & 31;
    int q  = cc & 3;          // quad within CV (c mod 16)/4
    float4 xv = ((const float4*)xc)[i];
    float4 d4 = ((const float4*)segb)[n*8 + q];
    float4 m4 = ((const float4*)segb)[n*8 + 4 + q];
    float4 o;
    o.x = xv.x + (d4.x > 0.0f ? m4.x / d4.x : 0.0f);
    o.y = xv.y + (d4.y > 0.0f ? m4.y / d4.y : 0.0f);
    o.z = xv.z + (d4.z > 0.0f ? m4.z / d4.z : 0.0f);
    o.w = xv.w + (d4.w > 0.0f ? m4.w / d4.w : 0.0f);
    ((float4*)out)[i] = o;
}

// ---------------- launch ------------------------------------------------------
extern "C" void kernel_launch(void* const* d_in, const int* in_sizes, int n_in,
                              void* d_out, int out_size, void* d_ws, size_t ws_size,
                              hipStream_t stream) {
    const float* x_center  = (const float*)d_in[0];
    const float* x_neigh   = (const float*)d_in[1];
    const float* rel_pos   = (const float*)d_in[2];
    const float* W_pos     = (const float*)d_in[3];
    const float* bn_gamma  = (const float*)d_in[4];
    const float* bn_beta   = (const float*)d_in[5];
    const float* W_mix     = (const float*)d_in[6];
    const float* b_mix     = (const float*)d_in[7];
    const float* W_val     = (const float*)d_in[8];
    const float* b_val     = (const float*)d_in[9];
    const int*   nidx      = (const int*)d_in[10];
    float* out = (float*)d_out;

    char*   ws    = (char*)d_ws;
    float*  stats = (float*)ws;                       // 9 floats
    float4* fold  = (float4*)(ws + 256);              // 128 float4
    float*  segb  = (float*)(ws + 4096);              // N*32 floats = 6.4 MB

    hipMemsetAsync(stats, 0, 64, stream);
    hipMemsetAsync(segb, 0, (size_t)N_PTS * 32 * sizeof(float), stream);

    k_stats<<<1024, 256, 0, stream>>>(rel_pos, stats);
    k_fold<<<1, 128, 0, stream>>>(stats, W_pos, bn_gamma, bn_beta, fold);
    k_main<<<(EDGES + 255) / 256, 256, 0, stream>>>(
        x_neigh, rel_pos, nidx, fold, W_mix, b_mix, W_val, b_val, segb);
    k_out<<<(N_PTS * CH / 4 + 255) / 256, 256, 0, stream>>>(x_center, segb, out);
}